// Round 3
// baseline (54.068 us; speedup 1.0000x reference)
//
#include <hip/hip_runtime.h>

#define NB 4
#define NP 6
#define NQ 4
#define NN 512
#define NWD 128
#define NROWS (NB * NP * NQ * NN)   // 49152
#define ALPHA 0.2f

__device__ __forceinline__ float lrelu(float x) {
    return x > 0.f ? x : ALPHA * x;
}

// Kernel 1: fused wa + s.
//   Phase A (per-block redundant, W is L2/L3-hot): wa1 = W@a1, wa2 = W@a2 -> LDS.
//   Phase B: s1[g], s2[g] for this block's 64 rows. Each wave handles 2 rows
//   per iteration: lane loads float4 at (rowpair*128 + lane*4); lanes 0-31
//   cover the even row, lanes 32-63 the odd row; 5-round butterfly within
//   each half-wave reduces both rows simultaneously.
__global__ __launch_bounds__(256) void s_fused_kernel(const float* __restrict__ st,
                                                      const float* __restrict__ W,
                                                      const float* __restrict__ a,
                                                      float* __restrict__ s1,
                                                      float* __restrict__ s2) {
    __shared__ float wa1[NWD];
    __shared__ float wa2[NWD];

    const int t = threadIdx.x;
    const int wid = t >> 6;
    const int lane = t & 63;

    // ---- Phase A ----
    {
        const int k = t & (NWD - 1);
        const float* av = a + (t >> 7) * NWD;   // a1 (t<128) or a2 (t>=128)
        const float* wr = W + (long)k * NWD;
        float s = 0.f;
        #pragma unroll
        for (int d = 0; d < NWD; d += 4) {
            const float4 wv  = *reinterpret_cast<const float4*>(wr + d);
            const float4 avv = *reinterpret_cast<const float4*>(av + d);
            s += wv.x * avv.x + wv.y * avv.y + wv.z * avv.z + wv.w * avv.w;
        }
        if (t < NWD) wa1[k] = s; else wa2[k] = s;
    }
    __syncthreads();

    // ---- Phase B ----
    const int l5 = lane & 31;                 // position within half-wave
    const float4 w1v = *reinterpret_cast<const float4*>(&wa1[l5 * 4]);
    const float4 w2v = *reinterpret_cast<const float4*>(&wa2[l5 * 4]);
    const long blockbase = (long)blockIdx.x * 64;   // 64 rows per block

    #pragma unroll
    for (int i = 0; i < 8; ++i) {
        const long rowpair = blockbase + (long)wid * 16 + i * 2;   // even row
        // lane*4 spans 2 rows x 128 cols: lanes 0-31 -> rowpair, 32-63 -> rowpair+1
        const float4 f = *reinterpret_cast<const float4*>(st + rowpair * NWD + lane * 4);
        float p1 = f.x * w1v.x + f.y * w1v.y + f.z * w1v.z + f.w * w1v.w;
        float p2 = f.x * w2v.x + f.y * w2v.y + f.z * w2v.z + f.w * w2v.w;
        #pragma unroll
        for (int off = 16; off > 0; off >>= 1) {
            p1 += __shfl_xor(p1, off);
            p2 += __shfl_xor(p2, off);
        }
        if (l5 == 0) {
            const long g = rowpair + (lane >> 5);
            s1[g] = p1;
            s2[g] = p2;
        }
    }
}

// Kernel 2: per output row: e[j] = lrelu(s1[i]+s2[j]); softmax over j;
// out[j] = lrelu(demand[j] * att[j]).  One wave per row, 8 cols/lane (2x float4).
__global__ __launch_bounds__(256) void main_kernel(const float* __restrict__ demand,
                                                   const float* __restrict__ s1,
                                                   const float* __restrict__ s2,
                                                   float* __restrict__ out) {
    int wid = threadIdx.x >> 6;
    int lane = threadIdx.x & 63;
    long g = (long)blockIdx.x * 4 + wid;     // global row, 0 .. NROWS-1
    long slice = g >> 9;                     // (b,p,q) index
    float s1i = s1[g];
    const float* s2s = s2 + slice * NN;

    const int c0 = lane * 4;
    const int c1 = 256 + lane * 4;
    const float4 sa = *reinterpret_cast<const float4*>(s2s + c0);
    const float4 sb = *reinterpret_cast<const float4*>(s2s + c1);

    float e[8];
    e[0] = lrelu(s1i + sa.x); e[1] = lrelu(s1i + sa.y);
    e[2] = lrelu(s1i + sa.z); e[3] = lrelu(s1i + sa.w);
    e[4] = lrelu(s1i + sb.x); e[5] = lrelu(s1i + sb.y);
    e[6] = lrelu(s1i + sb.z); e[7] = lrelu(s1i + sb.w);

    // wave max over all 512 cols
    float m = e[0];
    #pragma unroll
    for (int k = 1; k < 8; ++k) m = fmaxf(m, e[k]);
    #pragma unroll
    for (int off = 32; off > 0; off >>= 1) m = fmaxf(m, __shfl_xor(m, off));

    float p[8];
    float sum = 0.f;
    #pragma unroll
    for (int k = 0; k < 8; ++k) { p[k] = __expf(e[k] - m); sum += p[k]; }
    #pragma unroll
    for (int off = 32; off > 0; off >>= 1) sum += __shfl_xor(sum, off);
    const float inv = 1.f / sum;

    const float* drow = demand + g * NN;
    const float4 d0 = *reinterpret_cast<const float4*>(drow + c0);
    const float4 d1 = *reinterpret_cast<const float4*>(drow + c1);

    float4 o0, o1;
    o0.x = lrelu(d0.x * p[0] * inv); o0.y = lrelu(d0.y * p[1] * inv);
    o0.z = lrelu(d0.z * p[2] * inv); o0.w = lrelu(d0.w * p[3] * inv);
    o1.x = lrelu(d1.x * p[4] * inv); o1.y = lrelu(d1.y * p[5] * inv);
    o1.z = lrelu(d1.z * p[6] * inv); o1.w = lrelu(d1.w * p[7] * inv);

    float* orow = out + g * NN;
    *reinterpret_cast<float4*>(orow + c0) = o0;
    *reinterpret_cast<float4*>(orow + c1) = o1;
}

extern "C" void kernel_launch(void* const* d_in, const int* in_sizes, int n_in,
                              void* d_out, int out_size, void* d_ws, size_t ws_size,
                              hipStream_t stream) {
    const float* demand  = (const float*)d_in[0];
    const float* st_feat = (const float*)d_in[1];
    const float* W       = (const float*)d_in[2];
    const float* a       = (const float*)d_in[3];
    float* out = (float*)d_out;

    float* s1 = (float*)d_ws;                  // NROWS floats
    float* s2 = s1 + NROWS;                    // NROWS floats

    s_fused_kernel<<<NROWS / 64, 256, 0, stream>>>(st_feat, W, a, s1, s2);
    main_kernel<<<NROWS / 4, 256, 0, stream>>>(demand, s1, s2, out);
}